// Round 1
// 794.080 us; speedup vs baseline: 1.0048x; 1.0048x over previous
//
#include <hip/hip_runtime.h>
#include <hip/hip_bf16.h>

typedef __bf16 bf16x8 __attribute__((ext_vector_type(8)));
typedef float  f32x4  __attribute__((ext_vector_type(4)));

#define MFMA16(a, b, c) __builtin_amdgcn_mfma_f32_16x16x32_bf16((a), (b), (c), 0, 0, 0)

// Nontemporal (evict-first) f32x4 load: X is single-use streaming data; keep
// it from evicting the weight slices we want resident in L1.
__device__ __forceinline__ f32x4 nt_load4(const float* p) {
    return __builtin_nontemporal_load((const f32x4*)p);
}

// Pack weights into MFMA-B-fragment order so one wave b-load = 1 KB coalesced:
//   wp[((ks*CT + ct)*64 + lane)*8 + j] = W[(ct*16 + (lane&15))*K + ks*32 + (lane>>4)*8 + j]
// (lane = q*16+m16 holds B[k=q*8+j][n=m16] for col-tile ct, k-tile ks.)
__global__ void prep_weights(const float* __restrict__ W1, const float* __restrict__ W2,
                             const float* __restrict__ Wf1, const float* __restrict__ Wf2,
                             __bf16* __restrict__ w1p, __bf16* __restrict__ w2p,
                             __bf16* __restrict__ wf1p, __bf16* __restrict__ wf2b) {
    int t = blockIdx.x * 256 + threadIdx.x;
    int lane = t & 63, m16 = lane & 15, q = (lane >> 4) & 3;
    if (t < 16384) {  // W1: K=512, CT=16
        int ct = (t >> 6) & 15, ks = t >> 10;
        const float* s = W1 + (size_t)(ct * 16 + m16) * 512 + ks * 32 + q * 8;
        __bf16* d = w1p + (size_t)t * 8;
        for (int j = 0; j < 8; ++j) d[j] = (__bf16)s[j];
    }
    if (t < 4096) {   // W2: K=256, CT=8
        int ct = (t >> 6) & 7, ks = t >> 9;
        const float* s = W2 + (size_t)(ct * 16 + m16) * 256 + ks * 32 + q * 8;
        __bf16* d = w2p + (size_t)t * 8;
        for (int j = 0; j < 8; ++j) d[j] = (__bf16)s[j];
    }
    if (t < 1024) {   // Wf1: K=128, CT=4
        int ct = (t >> 6) & 3, ks = t >> 8;
        const float* s = Wf1 + (size_t)(ct * 16 + m16) * 128 + ks * 32 + q * 8;
        __bf16* d = wf1p + (size_t)t * 8;
        for (int j = 0; j < 8; ++j) d[j] = (__bf16)s[j];
    }
    if (t < 128) wf2b[t] = (__bf16)Wf2[t];
}

// One wave owns 32 rows end-to-end. R3 change: 256-thread blocks (4 waves on
// one CU) + a raw s_barrier at each ks so the 4 waves consume the SAME 16 KB
// weight ks-slice in lockstep -> 3 of 4 weight loads are L1 hits / MSHR
// merges (slice 16 KB < 32 KB L1; 2 blocks/CU -> 32 KB working set).
// Cuts weight L2 traffic 2.75 GB -> ~0.7 GB; X loads are nontemporal so the
// stream doesn't evict the slices. Raw s_barrier (NOT __syncthreads): hbuf is
// wave-private, so no fence -> no vmcnt(0) drain; X/weight prefetch pipelines
// stay in flight across the barrier.
// __launch_bounds__(256,2): 2 waves/EU -> 256-VGPR budget (R1-proven
// no-spill regime), 2 blocks/CU, LDS 2*67.6 KB = 135 KB < 160 KB.
__global__ __launch_bounds__(256, 2)
void mlp_kernel(const float* __restrict__ X,
                const __bf16* __restrict__ w1p,  const float* __restrict__ b1,
                const __bf16* __restrict__ w2p,  const float* __restrict__ b2,
                const __bf16* __restrict__ wf1p, const float* __restrict__ bf1,
                const __bf16* __restrict__ wf2b, const float* __restrict__ bf2,
                float* __restrict__ out) {
    // stride 264 bf16 = 528 B: 16B-aligned rows; read start-banks spread
    // 4*(m16+q) mod 32 -> balanced 8 words/bank (minimum) for b128 reads.
    __shared__ __align__(16) __bf16 hbuf[4][32][264];

    const int lane = threadIdx.x & 63;
    const int wave = threadIdx.x >> 6;   // 0..3
    const int m16  = lane & 15;
    const int q    = lane >> 4;
    const int row0 = blockIdx.x * 128 + wave * 32;
    __bf16(*hw)[264] = hbuf[wave];

    // ---------------- Layer 1: h1[32,256] = relu(X[32,512] @ W1^T + b1) ----
    f32x4 C1[2][16];
#pragma unroll
    for (int rt = 0; rt < 2; ++rt)
#pragma unroll
        for (int ct = 0; ct < 16; ++ct) C1[rt][ct] = (f32x4){0.f, 0.f, 0.f, 0.f};

    const float* xr0 = X + (size_t)(row0 + m16) * 512 + q * 8;
    const float* xr1 = xr0 + (size_t)16 * 512;
    f32x4 x00 = nt_load4(xr0);
    f32x4 x01 = nt_load4(xr0 + 4);
    f32x4 x10 = nt_load4(xr1);
    f32x4 x11 = nt_load4(xr1 + 4);

#pragma unroll
    for (int ks = 0; ks < 16; ++ks) {
        __builtin_amdgcn_s_barrier();    // keep 4 waves on the same ks-slice
        const __bf16* wp = w1p + (size_t)ks * 8192 + lane * 8;
        bf16x8 b0[8], b1v[8];
#pragma unroll
        for (int ct = 0; ct < 8; ++ct)       // batch 0: 1 KB coalesced each
            b0[ct] = *(const bf16x8*)(wp + ct * 512);

        bf16x8 a0, a1;
        a0[0] = (__bf16)x00[0]; a0[1] = (__bf16)x00[1]; a0[2] = (__bf16)x00[2]; a0[3] = (__bf16)x00[3];
        a0[4] = (__bf16)x01[0]; a0[5] = (__bf16)x01[1]; a0[6] = (__bf16)x01[2]; a0[7] = (__bf16)x01[3];
        a1[0] = (__bf16)x10[0]; a1[1] = (__bf16)x10[1]; a1[2] = (__bf16)x10[2]; a1[3] = (__bf16)x10[3];
        a1[4] = (__bf16)x11[0]; a1[5] = (__bf16)x11[1]; a1[6] = (__bf16)x11[2]; a1[7] = (__bf16)x11[3];

        if (ks < 15) {  // depth-1 X prefetch: lands during the 32 MFMAs below
            x00 = nt_load4(xr0 + (ks + 1) * 32);
            x01 = nt_load4(xr0 + (ks + 1) * 32 + 4);
            x10 = nt_load4(xr1 + (ks + 1) * 32);
            x11 = nt_load4(xr1 + (ks + 1) * 32 + 4);
        }
#pragma unroll
        for (int ct = 0; ct < 8; ++ct)       // batch 1 in flight over batch-0 MFMAs
            b1v[ct] = *(const bf16x8*)(wp + (8 + ct) * 512);

#pragma unroll
        for (int ct = 0; ct < 8; ++ct) {
            C1[0][ct] = MFMA16(a0, b0[ct], C1[0][ct]);
            C1[1][ct] = MFMA16(a1, b0[ct], C1[1][ct]);
        }
#pragma unroll
        for (int ct = 0; ct < 8; ++ct) {
            C1[0][8 + ct] = MFMA16(a0, b1v[ct], C1[0][8 + ct]);
            C1[1][8 + ct] = MFMA16(a1, b1v[ct], C1[1][8 + ct]);
        }
    }
#pragma unroll
    for (int ct = 0; ct < 16; ++ct) {
        float bias = b1[ct * 16 + m16];
#pragma unroll
        for (int rt = 0; rt < 2; ++rt)
#pragma unroll
            for (int r = 0; r < 4; ++r) {
                float v = C1[rt][ct][r] + bias;
                v = v > 0.f ? v : 0.f;
                hw[rt * 16 + q * 4 + r][ct * 16 + m16] = (__bf16)v;
            }
    }

    // ---------------- Layer 2: h2[32,128] = relu(h1 @ W2^T + b2) -----------
    f32x4 C2[2][8];
#pragma unroll
    for (int rt = 0; rt < 2; ++rt)
#pragma unroll
        for (int ct = 0; ct < 8; ++ct) C2[rt][ct] = (f32x4){0.f, 0.f, 0.f, 0.f};

#pragma unroll
    for (int ks = 0; ks < 8; ++ks) {
        __builtin_amdgcn_s_barrier();
        const __bf16* wp = w2p + (size_t)ks * 4096 + lane * 8;
        bf16x8 b[8];
#pragma unroll
        for (int ct = 0; ct < 8; ++ct) b[ct] = *(const bf16x8*)(wp + ct * 512);
        bf16x8 a0 = *(const bf16x8*)&hw[m16][ks * 32 + q * 8];
        bf16x8 a1 = *(const bf16x8*)&hw[16 + m16][ks * 32 + q * 8];
#pragma unroll
        for (int ct = 0; ct < 8; ++ct) {
            C2[0][ct] = MFMA16(a0, b[ct], C2[0][ct]);
            C2[1][ct] = MFMA16(a1, b[ct], C2[1][ct]);
        }
    }
#pragma unroll
    for (int ct = 0; ct < 8; ++ct) {
        float bias = b2[ct * 16 + m16];
#pragma unroll
        for (int rt = 0; rt < 2; ++rt)
#pragma unroll
            for (int r = 0; r < 4; ++r) {
                float v = C2[rt][ct][r] + bias;
                v = v > 0.f ? v : 0.f;
                hw[rt * 16 + q * 4 + r][ct * 16 + m16] = (__bf16)v;
            }
    }

    // ---------------- Layer 3: h3[32,64] = relu(h2 @ Wf1^T + bf1) ----------
    f32x4 C3[2][4];
#pragma unroll
    for (int rt = 0; rt < 2; ++rt)
#pragma unroll
        for (int ct = 0; ct < 4; ++ct) C3[rt][ct] = (f32x4){0.f, 0.f, 0.f, 0.f};

#pragma unroll
    for (int ks = 0; ks < 4; ++ks) {
        __builtin_amdgcn_s_barrier();
        const __bf16* wp = wf1p + (size_t)ks * 2048 + lane * 8;
        bf16x8 b[4];
#pragma unroll
        for (int ct = 0; ct < 4; ++ct) b[ct] = *(const bf16x8*)(wp + ct * 512);
        bf16x8 a0 = *(const bf16x8*)&hw[m16][ks * 32 + q * 8];
        bf16x8 a1 = *(const bf16x8*)&hw[16 + m16][ks * 32 + q * 8];
#pragma unroll
        for (int ct = 0; ct < 4; ++ct) {
            C3[0][ct] = MFMA16(a0, b[ct], C3[0][ct]);
            C3[1][ct] = MFMA16(a1, b[ct], C3[1][ct]);
        }
    }
#pragma unroll
    for (int ct = 0; ct < 4; ++ct) {
        float bias = bf1[ct * 16 + m16];
#pragma unroll
        for (int rt = 0; rt < 2; ++rt)
#pragma unroll
            for (int r = 0; r < 4; ++r) {
                float v = C3[rt][ct][r] + bias;
                v = v > 0.f ? v : 0.f;
                hw[rt * 16 + q * 4 + r][ct * 16 + m16] = (__bf16)v;
            }
    }

    // ---------------- Layer 4 + softmax (fp32): lane -> (row, class) -------
    {
        const int r = lane >> 1;   // 0..31
        const int c = lane & 1;
        float dot = 0.f;
#pragma unroll
        for (int j8 = 0; j8 < 8; ++j8) {
            bf16x8 hv = *(const bf16x8*)&hw[r][j8 * 8];
            bf16x8 wv = *(const bf16x8*)(wf2b + c * 64 + j8 * 8);
#pragma unroll
            for (int j = 0; j < 8; ++j) dot += (float)hv[j] * (float)wv[j];
        }
        float logit = dot + bf2[c];
        float other = __shfl_xor(logit, 1, 64);
        float mx = fmaxf(logit, other);
        float e0 = expf(logit - mx);
        float e1 = expf(other - mx);
        __builtin_nontemporal_store(e0 / (e0 + e1), &out[(size_t)(row0 + r) * 2 + c]);
    }
}

extern "C" void kernel_launch(void* const* d_in, const int* in_sizes, int n_in,
                              void* d_out, int out_size, void* d_ws, size_t ws_size,
                              hipStream_t stream) {
    const float* X   = (const float*)d_in[0];
    const float* W1  = (const float*)d_in[1];
    const float* b1  = (const float*)d_in[2];
    const float* W2  = (const float*)d_in[3];
    const float* b2  = (const float*)d_in[4];
    const float* Wf1 = (const float*)d_in[5];
    const float* bf1 = (const float*)d_in[6];
    const float* Wf2 = (const float*)d_in[7];
    const float* bf2 = (const float*)d_in[8];
    float* out = (float*)d_out;

    const int N = in_sizes[0] / 512;  // 262144

    __bf16* w1p  = (__bf16*)d_ws;            // 16384*8  = 131072 elems
    __bf16* w2p  = w1p  + 131072;            // 4096*8   = 32768
    __bf16* wf1p = w2p  + 32768;             // 1024*8   = 8192
    __bf16* wf2b = wf1p + 8192;              // 128

    prep_weights<<<64, 256, 0, stream>>>(W1, W2, Wf1, Wf2, w1p, w2p, wf1p, wf2b);
    mlp_kernel<<<N / 128, 256, 0, stream>>>(X, w1p, b1, w2p, b2, wf1p, bf1,
                                            wf2b, bf2, out);
}

// Round 2
// 752.505 us; speedup vs baseline: 1.0603x; 1.0552x over previous
//
#include <hip/hip_runtime.h>
#include <hip/hip_bf16.h>

typedef __bf16 bf16x8 __attribute__((ext_vector_type(8)));
typedef float  f32x4  __attribute__((ext_vector_type(4)));

#define MFMA16(a, b, c) __builtin_amdgcn_mfma_f32_16x16x32_bf16((a), (b), (c), 0, 0, 0)

// Direct global->LDS DMA, 16 B per lane. LDS dest is wave-uniform base +
// lane*16 (HW rule); global src is per-lane.
#define GLDS16(gp, lp) __builtin_amdgcn_global_load_lds(                      \
    (const __attribute__((address_space(1))) void*)(gp),                      \
    (__attribute__((address_space(3))) void*)(lp), 16, 0, 0)
#define SBAR()   __builtin_amdgcn_s_barrier()
#define SCHED0() __builtin_amdgcn_sched_barrier(0)

// Nontemporal (evict-first) f32x4 load: X is single-use streaming data.
__device__ __forceinline__ f32x4 nt_load4(const float* p) {
    return __builtin_nontemporal_load((const f32x4*)p);
}

// Pack weights into MFMA-B-fragment order so one wave b-load = 1 KB coalesced:
//   wp[((ks*CT + ct)*64 + lane)*8 + j] = W[(ct*16 + (lane&15))*K + ks*32 + (lane>>4)*8 + j]
__global__ void prep_weights(const float* __restrict__ W1, const float* __restrict__ W2,
                             const float* __restrict__ Wf1, const float* __restrict__ Wf2,
                             __bf16* __restrict__ w1p, __bf16* __restrict__ w2p,
                             __bf16* __restrict__ wf1p, __bf16* __restrict__ wf2b) {
    int t = blockIdx.x * 256 + threadIdx.x;
    int lane = t & 63, m16 = lane & 15, q = (lane >> 4) & 3;
    if (t < 16384) {  // W1: K=512, CT=16
        int ct = (t >> 6) & 15, ks = t >> 10;
        const float* s = W1 + (size_t)(ct * 16 + m16) * 512 + ks * 32 + q * 8;
        __bf16* d = w1p + (size_t)t * 8;
        for (int j = 0; j < 8; ++j) d[j] = (__bf16)s[j];
    }
    if (t < 4096) {   // W2: K=256, CT=8
        int ct = (t >> 6) & 7, ks = t >> 9;
        const float* s = W2 + (size_t)(ct * 16 + m16) * 256 + ks * 32 + q * 8;
        __bf16* d = w2p + (size_t)t * 8;
        for (int j = 0; j < 8; ++j) d[j] = (__bf16)s[j];
    }
    if (t < 1024) {   // Wf1: K=128, CT=4
        int ct = (t >> 6) & 3, ks = t >> 8;
        const float* s = Wf1 + (size_t)(ct * 16 + m16) * 128 + ks * 32 + q * 8;
        __bf16* d = wf1p + (size_t)t * 8;
        for (int j = 0; j < 8; ++j) d[j] = (__bf16)s[j];
    }
    if (t < 128) wf2b[t] = (__bf16)Wf2[t];
}

// R2: weights served from block-shared LDS (DS pipe) instead of per-wave
// global loads (VMEM pipe). Rationale: per-wave weight register-fill was
// 10.75 MB/CU on the VMEM return path (~70 us) stacked on the X HBM stream
// (85 us) -> same pipe. Staging 336 KB once per 256-row block moves the 8x
// read amplification onto the DS pipe (~40 us, hidden under X-HBM).
// 512 threads = 8 waves = same 8 waves/CU (2/SIMD) occupancy as before.
//
// LDS map (bf16 elems, 75776 total = 148 KB):
//   [0     .. 16384) W1 slice dbuf (2 x 16 KB) -- ALIASES hbuf waves 0/1;
//                    safe: h1 written only after last W1 read + barrier.
//   [w*8448.. +8448) hbuf wave w (32 rows x stride 264), w = 0..7 (ends 67584)
//   [67584 .. 71680) W2 slice dbuf buf0 (8 KB) -> later Wf1[0..8KB)
//   [71680 .. 75776) W2 slice dbuf buf1 (8 KB) -> later Wf1[8..16KB)
//
// Sync: raw s_barrier + counted vmcnt (vmcnt(4) keeps the 4 X-prefetch loads
// in flight across the barrier; never drain to 0 in the L1 loop).
__global__ __launch_bounds__(512, 2)
void mlp_kernel(const float* __restrict__ X,
                const __bf16* __restrict__ w1p,  const float* __restrict__ b1,
                const __bf16* __restrict__ w2p,  const float* __restrict__ b2,
                const __bf16* __restrict__ wf1p, const float* __restrict__ bf1,
                const __bf16* __restrict__ wf2b, const float* __restrict__ bf2,
                float* __restrict__ out) {
    __shared__ __align__(16) __bf16 smem[75776];

    const int lane = threadIdx.x & 63;
    const int wave = threadIdx.x >> 6;   // 0..7
    const int m16  = lane & 15;
    const int q    = lane >> 4;
    const int row0 = blockIdx.x * 256 + wave * 32;
    __bf16(*hw)[264] = (__bf16(*)[264])&smem[wave * 8448];

    // ---------------- Layer 1: h1[32,256] = relu(X[32,512] @ W1^T + b1) ----
    f32x4 C1[2][16];
#pragma unroll
    for (int rt = 0; rt < 2; ++rt)
#pragma unroll
        for (int ct = 0; ct < 16; ++ct) C1[rt][ct] = (f32x4){0.f, 0.f, 0.f, 0.f};

    const float* xr0 = X + (size_t)(row0 + m16) * 512 + q * 8;
    const float* xr1 = xr0 + (size_t)16 * 512;

    // Prologue: stage W1 slice 0 (16 KB, 2 KB/wave), then X tile 0.
    {
        const char* g = (const char*)w1p + wave * 2048 + lane * 16;
        GLDS16(g,        &smem[wave * 1024]);
        GLDS16(g + 1024, &smem[wave * 1024 + 512]);
    }
    SCHED0();
    f32x4 x00 = nt_load4(xr0);
    f32x4 x01 = nt_load4(xr0 + 4);
    f32x4 x10 = nt_load4(xr1);
    f32x4 x11 = nt_load4(xr1 + 4);
    asm volatile("s_waitcnt vmcnt(4)" ::: "memory");  // drain stage, keep X
    SBAR(); SCHED0();

#pragma unroll
    for (int ks = 0; ks < 16; ++ks) {
        const __bf16* wl = &smem[(ks & 1) * 8192 + lane * 8];
        if (ks < 15) {  // stage next W1 slice into the other buffer
            const char* g = (const char*)w1p + (size_t)(ks + 1) * 16384
                          + wave * 2048 + lane * 16;
            __bf16* l = &smem[((ks + 1) & 1) * 8192 + wave * 1024];
            GLDS16(g, l);
            GLDS16(g + 1024, l + 512);
        } else {        // ks==15: stage W2 slice 0 (8 KB, 1 KB/wave) into w2s0
            const char* g = (const char*)w2p + wave * 1024 + lane * 16;
            GLDS16(g, &smem[67584 + wave * 512]);
        }
        SCHED0();       // pin stage issue before everything below

        bf16x8 b0[8], b1v[8];
#pragma unroll
        for (int ct = 0; ct < 8; ++ct)
            b0[ct] = *(const bf16x8*)(wl + ct * 512);

        bf16x8 a0, a1;
        a0[0] = (__bf16)x00[0]; a0[1] = (__bf16)x00[1]; a0[2] = (__bf16)x00[2]; a0[3] = (__bf16)x00[3];
        a0[4] = (__bf16)x01[0]; a0[5] = (__bf16)x01[1]; a0[6] = (__bf16)x01[2]; a0[7] = (__bf16)x01[3];
        a1[0] = (__bf16)x10[0]; a1[1] = (__bf16)x10[1]; a1[2] = (__bf16)x10[2]; a1[3] = (__bf16)x10[3];
        a1[4] = (__bf16)x11[0]; a1[5] = (__bf16)x11[1]; a1[6] = (__bf16)x11[2]; a1[7] = (__bf16)x11[3];

        if (ks < 15) {  // depth-1 X prefetch: lands during the 32 MFMAs below
            x00 = nt_load4(xr0 + (ks + 1) * 32);
            x01 = nt_load4(xr0 + (ks + 1) * 32 + 4);
            x10 = nt_load4(xr1 + (ks + 1) * 32);
            x11 = nt_load4(xr1 + (ks + 1) * 32 + 4);
        }
#pragma unroll
        for (int ct = 0; ct < 8; ++ct)
            b1v[ct] = *(const bf16x8*)(wl + (8 + ct) * 512);

#pragma unroll
        for (int ct = 0; ct < 8; ++ct) {
            C1[0][ct] = MFMA16(a0, b0[ct], C1[0][ct]);
            C1[1][ct] = MFMA16(a1, b0[ct], C1[1][ct]);
        }
#pragma unroll
        for (int ct = 0; ct < 8; ++ct) {
            C1[0][8 + ct] = MFMA16(a0, b1v[ct], C1[0][8 + ct]);
            C1[1][8 + ct] = MFMA16(a1, b1v[ct], C1[1][8 + ct]);
        }

        if (ks < 15) {  // wait own staging done; X prefetch stays in flight
            asm volatile("s_waitcnt vmcnt(4)" ::: "memory");
        } else {
            asm volatile("s_waitcnt vmcnt(0)" ::: "memory");
        }
        SBAR(); SCHED0();
    }
#pragma unroll
    for (int ct = 0; ct < 16; ++ct) {
        float bias = b1[ct * 16 + m16];
#pragma unroll
        for (int rt = 0; rt < 2; ++rt)
#pragma unroll
            for (int r = 0; r < 4; ++r) {
                float v = C1[rt][ct][r] + bias;
                v = v > 0.f ? v : 0.f;
                hw[rt * 16 + q * 4 + r][ct * 16 + m16] = (__bf16)v;
            }
    }

    // ---------------- Layer 2: h2[32,128] = relu(h1 @ W2^T + b2) -----------
    f32x4 C2[2][8];
#pragma unroll
    for (int rt = 0; rt < 2; ++rt)
#pragma unroll
        for (int ct = 0; ct < 8; ++ct) C2[rt][ct] = (f32x4){0.f, 0.f, 0.f, 0.f};

#pragma unroll
    for (int ks = 0; ks < 8; ++ks) {
        const __bf16* wl = &smem[67584 + (ks & 1) * 4096 + lane * 8];
        if (ks < 7) {   // stage next W2 slice into the other buffer
            const char* g = (const char*)w2p + (size_t)(ks + 1) * 8192
                          + wave * 1024 + lane * 16;
            GLDS16(g, &smem[67584 + ((ks + 1) & 1) * 4096 + wave * 512]);
        } else {        // ks==7: stage Wf1 lo half (8 KB) into buf0 (now free)
            const char* g = (const char*)wf1p + wave * 1024 + lane * 16;
            GLDS16(g, &smem[67584 + wave * 512]);
        }
        SCHED0();
        bf16x8 b[8];
#pragma unroll
        for (int ct = 0; ct < 8; ++ct)
            b[ct] = *(const bf16x8*)(wl + ct * 512);
        bf16x8 a0 = *(const bf16x8*)&hw[m16][ks * 32 + q * 8];
        bf16x8 a1 = *(const bf16x8*)&hw[16 + m16][ks * 32 + q * 8];
#pragma unroll
        for (int ct = 0; ct < 8; ++ct) {
            C2[0][ct] = MFMA16(a0, b[ct], C2[0][ct]);
            C2[1][ct] = MFMA16(a1, b[ct], C2[1][ct]);
        }
        asm volatile("s_waitcnt vmcnt(0)" ::: "memory");
        SBAR(); SCHED0();
    }
    {   // stage Wf1 hi half (8 KB) into buf1 (free after ks=7 barrier);
        // consumed from layer-3 ks=2 on (barrier there).
        const char* g = (const char*)wf1p + 8192 + wave * 1024 + lane * 16;
        GLDS16(g, &smem[71680 + wave * 512]);
    }
#pragma unroll
    for (int ct = 0; ct < 8; ++ct) {
        float bias = b2[ct * 16 + m16];
#pragma unroll
        for (int rt = 0; rt < 2; ++rt)
#pragma unroll
            for (int r = 0; r < 4; ++r) {
                float v = C2[rt][ct][r] + bias;
                v = v > 0.f ? v : 0.f;
                hw[rt * 16 + q * 4 + r][ct * 16 + m16] = (__bf16)v;
            }
    }

    // ---------------- Layer 3: h3[32,64] = relu(h2 @ Wf1^T + bf1) ----------
    f32x4 C3[2][4];
#pragma unroll
    for (int rt = 0; rt < 2; ++rt)
#pragma unroll
        for (int ct = 0; ct < 4; ++ct) C3[rt][ct] = (f32x4){0.f, 0.f, 0.f, 0.f};

#pragma unroll
    for (int ks = 0; ks < 4; ++ks) {
        if (ks == 2) {  // Wf1 hi half must be staged by ALL waves
            asm volatile("s_waitcnt vmcnt(0)" ::: "memory");
            SBAR(); SCHED0();
        }
        const __bf16* wl = &smem[67584 + ks * 2048 + lane * 8];
        bf16x8 b[4];
#pragma unroll
        for (int ct = 0; ct < 4; ++ct)
            b[ct] = *(const bf16x8*)(wl + ct * 512);
        bf16x8 a0 = *(const bf16x8*)&hw[m16][ks * 32 + q * 8];
        bf16x8 a1 = *(const bf16x8*)&hw[16 + m16][ks * 32 + q * 8];
#pragma unroll
        for (int ct = 0; ct < 4; ++ct) {
            C3[0][ct] = MFMA16(a0, b[ct], C3[0][ct]);
            C3[1][ct] = MFMA16(a1, b[ct], C3[1][ct]);
        }
    }
#pragma unroll
    for (int ct = 0; ct < 4; ++ct) {
        float bias = bf1[ct * 16 + m16];
#pragma unroll
        for (int rt = 0; rt < 2; ++rt)
#pragma unroll
            for (int r = 0; r < 4; ++r) {
                float v = C3[rt][ct][r] + bias;
                v = v > 0.f ? v : 0.f;
                hw[rt * 16 + q * 4 + r][ct * 16 + m16] = (__bf16)v;
            }
    }

    // ---------------- Layer 4 + softmax (fp32): lane -> (row, class) -------
    {
        const int r = lane >> 1;   // 0..31
        const int c = lane & 1;
        float dot = 0.f;
#pragma unroll
        for (int j8 = 0; j8 < 8; ++j8) {
            bf16x8 hv = *(const bf16x8*)&hw[r][j8 * 8];
            bf16x8 wv = *(const bf16x8*)(wf2b + c * 64 + j8 * 8);
#pragma unroll
            for (int j = 0; j < 8; ++j) dot += (float)hv[j] * (float)wv[j];
        }
        float logit = dot + bf2[c];
        float other = __shfl_xor(logit, 1, 64);
        float mx = fmaxf(logit, other);
        float e0 = expf(logit - mx);
        float e1 = expf(other - mx);
        __builtin_nontemporal_store(e0 / (e0 + e1), &out[(size_t)(row0 + r) * 2 + c]);
    }
}

extern "C" void kernel_launch(void* const* d_in, const int* in_sizes, int n_in,
                              void* d_out, int out_size, void* d_ws, size_t ws_size,
                              hipStream_t stream) {
    const float* X   = (const float*)d_in[0];
    const float* W1  = (const float*)d_in[1];
    const float* b1  = (const float*)d_in[2];
    const float* W2  = (const float*)d_in[3];
    const float* b2  = (const float*)d_in[4];
    const float* Wf1 = (const float*)d_in[5];
    const float* bf1 = (const float*)d_in[6];
    const float* Wf2 = (const float*)d_in[7];
    const float* bf2 = (const float*)d_in[8];
    float* out = (float*)d_out;

    const int N = in_sizes[0] / 512;  // 262144

    __bf16* w1p  = (__bf16*)d_ws;            // 16384*8  = 131072 elems
    __bf16* w2p  = w1p  + 131072;            // 4096*8   = 32768
    __bf16* wf1p = w2p  + 32768;             // 1024*8   = 8192
    __bf16* wf2b = wf1p + 8192;              // 128

    prep_weights<<<64, 256, 0, stream>>>(W1, W2, Wf1, Wf2, w1p, w2p, wf1p, wf2b);
    mlp_kernel<<<N / 256, 512, 0, stream>>>(X, w1p, b1, w2p, b2, wf1p, bf1,
                                            wf2b, bf2, out);
}